// Round 13
// baseline (686.493 us; speedup 1.0000x reference)
//
#include <hip/hip_runtime.h>
#include <hip/hip_cooperative_groups.h>

namespace cg = cooperative_groups;

#define LSEQ  512
#define NNODE 2048
#define CDIM  128
#define EMAX  131072
#define NLAY  3
#define DCAP  768

typedef float f32x4 __attribute__((ext_vector_type(4)));
typedef unsigned short u16x8 __attribute__((ext_vector_type(8)));

static __device__ __forceinline__ unsigned short f2bf(float x) {
  unsigned u = __float_as_uint(x);
  unsigned r = (u + 0x7fffu + ((u >> 16) & 1u)) >> 16;
  return (unsigned short)r;
}

static __device__ __forceinline__ void mfma16(f32x4& d, f32x4 a, f32x4 b) {
  asm("v_mfma_f32_16x16x32_bf16 %0, %1, %2, %0" : "+v"(d) : "v"(a), "v"(b));
}

// ---------------- CSR build (mask-filtered, per call) ----------------
__global__ void k_zero(int* __restrict__ p, int n) {
  int i = blockIdx.x * blockDim.x + threadIdx.x;
  if (i < n) p[i] = 0;
}

__global__ void k_count(const int* __restrict__ dst, const float* __restrict__ msk,
                        int* __restrict__ cnt) {
  int e = blockIdx.x * 256 + threadIdx.x;
  if (msk[e] != 0.f) atomicAdd(&cnt[dst[e]], 1);
}

__global__ __launch_bounds__(256) void k_scan(const int* __restrict__ cnt,
                                              int* __restrict__ rowp) {
  __shared__ int lds[256];
  int t = threadIdx.x;
  int loc[8];
  int s = 0;
#pragma unroll
  for (int i = 0; i < 8; ++i) { loc[i] = s; s += cnt[t * 8 + i]; }
  lds[t] = s;
  __syncthreads();
  for (int off = 1; off < 256; off <<= 1) {
    int v = (t >= off) ? lds[t - off] : 0;
    __syncthreads();
    lds[t] += v;
    __syncthreads();
  }
  int base = t ? lds[t - 1] : 0;
#pragma unroll
  for (int i = 0; i < 8; ++i) rowp[t * 8 + i] = base + loc[i];
  if (t == 255) rowp[NNODE] = lds[255];
}

__global__ void k_fill(const int* __restrict__ src, const int* __restrict__ dst,
                       const float* __restrict__ msk, const int* __restrict__ rowp,
                       int* __restrict__ cur, int* __restrict__ eS,
                       int* __restrict__ eD) {
  int e = blockIdx.x * 256 + threadIdx.x;
  if (msk[e] != 0.f) {
    int n = dst[e];
    int slot = atomicAdd(&cur[n], 1);
    int p = rowp[n] + slot;
    eS[p] = src[e];
    eD[p] = n;
  }
}

// ---------------- mega kernel args ----------------
struct MegaArgs {
  const float *seq, *pair, *bppm, *coords;
  const float *Win, *Wq, *Wk, *Wv, *Wo, *We, *wd, *wx, *lng, *lnb;
  const int *eS, *eD, *rowp;
  float *hA, *hB, *hqA, *hkA, *hvA, *hqB, *hkB, *hvB;
  float *logits, *spre, *agg, *x0, *x1, *out;
  unsigned short *Ebf, *WeT;
};

#define SM_BYTES 51200

// ------- phase bodies (operate on shared arena sm) -------

static __device__ void hinq_body(char* sm, int vb, const float* seq,
                                 const float* Win, const float* Wq0,
                                 const float* Wk0, const float* Wv0, float* h,
                                 float* hq, float* hk, float* hv) {
  float(*sSeq)[64] = (float(*)[64])(sm);
  float(*sW)[128] = (float(*)[128])(sm + 1024);
  float(*sH)[128] = (float(*)[128])(sm + 33792);
  const int tid = threadIdx.x;
  const int c = tid & 127, g = tid >> 7;
  const int nb = vb * 4;

  float a0 = 0.f, a1 = 0.f;
  for (int kc = 0; kc < 10; ++kc) {
    if (tid < 64) {
      int n = tid >> 4, t4 = tid & 15;
      *(float4*)&sSeq[n][t4 * 4] =
          *(const float4*)&seq[(size_t)(nb + n) * 640 + kc * 64 + t4 * 4];
    }
    const float4* wsrc = (const float4*)(Win + (size_t)kc * 64 * CDIM);
#pragma unroll
    for (int i = 0; i < 8; ++i) ((float4*)sW)[tid + i * 256] = wsrc[tid + i * 256];
    __syncthreads();
#pragma unroll 8
    for (int k = 0; k < 64; ++k) {
      float w = sW[k][c];
      a0 += sSeq[g * 2][k] * w;
      a1 += sSeq[g * 2 + 1][k] * w;
    }
    __syncthreads();
  }
  h[(size_t)(nb + g * 2) * CDIM + c] = a0;
  h[(size_t)(nb + g * 2 + 1) * CDIM + c] = a1;
  sH[g * 2][c] = a0;
  sH[g * 2 + 1][c] = a1;
  __syncthreads();

  for (int ws = 0; ws < 3; ++ws) {
    const float* W = ws == 0 ? Wq0 : (ws == 1 ? Wk0 : Wv0);
    float b0 = 0.f, b1 = 0.f;
    for (int kc = 0; kc < 2; ++kc) {
      const float4* wsrc = (const float4*)(W + (size_t)kc * 64 * CDIM);
#pragma unroll
      for (int i = 0; i < 8; ++i) ((float4*)sW)[tid + i * 256] = wsrc[tid + i * 256];
      __syncthreads();
#pragma unroll 8
      for (int k = 0; k < 64; ++k) {
        float w = sW[k][c];
        b0 += sH[g * 2][kc * 64 + k] * w;
        b1 += sH[g * 2 + 1][kc * 64 + k] * w;
      }
      __syncthreads();
    }
    float* o = ws == 0 ? hq : (ws == 1 ? hk : hv);
    o[(size_t)(nb + g * 2) * CDIM + c] = b0;
    o[(size_t)(nb + g * 2 + 1) * CDIM + c] = b1;
  }
  __syncthreads();
}

static __device__ void edge_body(char* sm, int vb, int gather,
                                 const float* pair, const float* bppm,
                                 const int* eS, const int* eD,
                                 unsigned short* Ebf, float* logits,
                                 float* spre, const float* xc, const float* hq,
                                 const float* hk, const unsigned short* WeTl,
                                 const float* Wel, const float* wdl,
                                 const float* wxl) {
  unsigned char* sA = (unsigned char*)sm;
  float* sEb = (float*)(sm + 16384);
  float(*sPart)[64] = (float(*)[64])(sm + 49152);
  int* sS = (int*)(sm + 50176);
  int* sD = (int*)(sm + 50432);
  float* sBp = (float*)(sm + 50688);
  float* sD2 = (float*)(sm + 50944);

  const int tid = threadIdx.x;
  const int w = tid >> 6, l = tid & 63;
  const int li = l & 15, gi = l >> 4;
  const int p0 = vb * 64;

  f32x4 stg[4];
  if (!gather) {
    const f32x4* gE = (const f32x4*)((const char*)Ebf + (size_t)p0 * 256);
#pragma unroll
    for (int r = 0; r < 4; ++r) stg[r] = gE[r * 256 + tid];
  } else {
#pragma unroll
    for (int i = 0; i < 4; ++i) {
      int slot = tid + i * 256;
      int q = slot >> 4, t = slot & 15;
      int p = p0 + q;
      int s_ = eS[p], d_ = eD[p];
      int j = d_ - ((s_ >> 9) << 9);
      const float* rp = pair + ((size_t)s_ * LSEQ + j) * CDIM + t * 8;
      float4 v0 = *(const float4*)rp;
      float4 v1 = *(const float4*)(rp + 4);
      u16x8 ov;
      ov[0] = f2bf(v0.x); ov[1] = f2bf(v0.y); ov[2] = f2bf(v0.z); ov[3] = f2bf(v0.w);
      ov[4] = f2bf(v1.x); ov[5] = f2bf(v1.y); ov[6] = f2bf(v1.z); ov[7] = f2bf(v1.w);
      int m = q >> 4, lie = q & 15, ks = t >> 2, gie = t & 3;
      int rel = ((ks * 4 + m) * 64 + gie * 16 + lie) * 16;
      *(u16x8*)(sA + rel) = ov;
      *(u16x8*)((char*)Ebf + (size_t)p0 * 256 + rel) = ov;
    }
  }

  f32x4 bf[2][4];
#pragma unroll
  for (int nt = 0; nt < 2; ++nt) {
    int c = w * 32 + nt * 16 + li;
#pragma unroll
    for (int ks = 0; ks < 4; ++ks) {
      int k0 = ks * 32 + gi * 8;
      bf[nt][ks] = *(const f32x4*)((const char*)WeTl + (size_t)(c * 128 + k0) * 2);
    }
  }

  if (tid < 64) {
    int p = p0 + tid;
    int s_ = eS[p], d_ = eD[p];
    sS[tid] = s_; sD[tid] = d_;
    int j = d_ - ((s_ >> 9) << 9);
    float rx = xc[3 * s_ + 0] - xc[3 * d_ + 0];
    float ry = xc[3 * s_ + 1] - xc[3 * d_ + 1];
    float rz = xc[3 * s_ + 2] - xc[3 * d_ + 2];
    sD2[tid] = rx * rx + ry * ry + rz * rz;
    sBp[tid] = bppm[(size_t)s_ * LSEQ + j];
  }

  f32x4* sA4 = (f32x4*)sA;
  if (!gather) {
#pragma unroll
    for (int r = 0; r < 4; ++r) sA4[r * 256 + tid] = stg[r];
  }
  __syncthreads();

  f32x4 acc[4][2];
#pragma unroll
  for (int m = 0; m < 4; ++m)
#pragma unroll
    for (int nt = 0; nt < 2; ++nt) acc[m][nt] = (f32x4){0.f, 0.f, 0.f, 0.f};

#pragma unroll
  for (int ks = 0; ks < 4; ++ks) {
    f32x4 af[4];
#pragma unroll
    for (int m = 0; m < 4; ++m) af[m] = sA4[(ks * 4 + m) * 64 + l];
#pragma unroll
    for (int m = 0; m < 4; ++m) {
      mfma16(acc[m][0], af[m], bf[0][ks]);
      mfma16(acc[m][1], af[m], bf[1][ks]);
    }
  }

  const int c0 = w * 32 + li, c1 = c0 + 16;
  const float w128_0 = Wel[128 * 128 + c0], w128_1 = Wel[128 * 128 + c1];
  const float wd0 = wdl[c0], wd1 = wdl[c1];
#pragma unroll
  for (int m = 0; m < 4; ++m) {
#pragma unroll
    for (int r = 0; r < 4; ++r) {
      int el = m * 16 + gi * 4 + r;
      float bp = sBp[el], d2v = sD2[el];
      float eb0 = fmaxf(acc[m][0][r] + bp * w128_0 + d2v * wd0, 0.f);
      float eb1 = fmaxf(acc[m][1][r] + bp * w128_1 + d2v * wd1, 0.f);
      int swz = (el & 7) << 2;
      sEb[el * 128 + (c0 ^ swz)] = eb0;
      sEb[el * 128 + (c1 ^ swz)] = eb1;
    }
  }
  __syncthreads();

  {
    const int s_ = sS[l], d_ = sD[l];
    const int swz = (l & 7) << 2;
    const float* hkr = hk + (size_t)s_ * CDIM + w * 32;
    const float* hqr = hq + (size_t)d_ * CDIM + w * 32;
    const float* wxr = wxl + w * 32;
    float lp = 0.f, sp = 0.f;
#pragma unroll
    for (int k = 0; k < 8; ++k) {
      f32x4 ebq = *(const f32x4*)&sEb[l * 128 + ((w * 32 + k * 4) ^ swz)];
      float4 hkq = *(const float4*)(hkr + k * 4);
      float4 hqq = *(const float4*)(hqr + k * 4);
      float4 wxq = *(const float4*)(wxr + k * 4);
      float keb0 = ebq[0] + hkq.x, keb1 = ebq[1] + hkq.y;
      float keb2 = ebq[2] + hkq.z, keb3 = ebq[3] + hkq.w;
      lp += hqq.x * keb0 + hqq.y * keb1 + hqq.z * keb2 + hqq.w * keb3;
      sp += wxq.x * keb0 + wxq.y * keb1 + wxq.z * keb2 + wxq.w * keb3;
    }
    logits[(size_t)(p0 + l) * 4 + w] = lp * 0.17677669529663689f;
    sPart[w][l] = sp;
  }
  __syncthreads();
  if (tid < 64)
    spre[p0 + tid] =
        tanhf(sPart[0][tid] + sPart[1][tid] + sPart[2][tid] + sPart[3][tid]);
  __syncthreads();
}

static __device__ void aggf_body(char* sm, int n, const int* rowp,
                                 const float4* lg4, const float* spre,
                                 const float* hvin, const int* eS,
                                 const float* xc, float* xn, float* agg) {
  float4* sLg = (float4*)sm;
  float(*sA)[4] = (float(*)[4])(sm + 12288);
  int* sSe = (int*)(sm + 16384);
  float(*sRed)[4] = (float(*)[4])(sm + 17408);
  float4(*sAccF)[32] = (float4(*)[32])(sm + 17472);
  float(*sDx)[3] = (float(*)[3])(sm + 21568);

  const int tid = threadIdx.x;
  const int w = tid >> 6, lane = tid & 63;
  const int st = rowp[n], deg = rowp[n + 1] - st;
  const bool cached = (deg <= DCAP);

  float m0 = -3e38f, m1 = -3e38f, m2 = -3e38f, m3 = -3e38f;
  for (int i = tid; i < deg; i += 256) {
    float4 lg = lg4[st + i];
    if (cached) sLg[i] = lg;
    m0 = fmaxf(m0, lg.x); m1 = fmaxf(m1, lg.y);
    m2 = fmaxf(m2, lg.z); m3 = fmaxf(m3, lg.w);
  }
#pragma unroll
  for (int o = 32; o; o >>= 1) {
    m0 = fmaxf(m0, __shfl_xor(m0, o)); m1 = fmaxf(m1, __shfl_xor(m1, o));
    m2 = fmaxf(m2, __shfl_xor(m2, o)); m3 = fmaxf(m3, __shfl_xor(m3, o));
  }
  if (!lane) { sRed[w][0] = m0; sRed[w][1] = m1; sRed[w][2] = m2; sRed[w][3] = m3; }
  __syncthreads();
  m0 = fmaxf(fmaxf(sRed[0][0], sRed[1][0]), fmaxf(sRed[2][0], sRed[3][0]));
  m1 = fmaxf(fmaxf(sRed[0][1], sRed[1][1]), fmaxf(sRed[2][1], sRed[3][1]));
  m2 = fmaxf(fmaxf(sRed[0][2], sRed[1][2]), fmaxf(sRed[2][2], sRed[3][2]));
  m3 = fmaxf(fmaxf(sRed[0][3], sRed[1][3]), fmaxf(sRed[2][3], sRed[3][3]));
  __syncthreads();

  float dn0 = 0.f, dn1 = 0.f, dn2 = 0.f, dn3 = 0.f;
  for (int i = tid; i < deg; i += 256) {
    float4 lg = cached ? sLg[i] : lg4[st + i];
    dn0 += __expf(lg.x - m0); dn1 += __expf(lg.y - m1);
    dn2 += __expf(lg.z - m2); dn3 += __expf(lg.w - m3);
  }
#pragma unroll
  for (int o = 32; o; o >>= 1) {
    dn0 += __shfl_xor(dn0, o); dn1 += __shfl_xor(dn1, o);
    dn2 += __shfl_xor(dn2, o); dn3 += __shfl_xor(dn3, o);
  }
  if (!lane) { sRed[w][0] = dn0; sRed[w][1] = dn1; sRed[w][2] = dn2; sRed[w][3] = dn3; }
  __syncthreads();
  dn0 = sRed[0][0] + sRed[1][0] + sRed[2][0] + sRed[3][0];
  dn1 = sRed[0][1] + sRed[1][1] + sRed[2][1] + sRed[3][1];
  dn2 = sRed[0][2] + sRed[1][2] + sRed[2][2] + sRed[3][2];
  dn3 = sRed[0][3] + sRed[1][3] + sRed[2][3] + sRed[3][3];
  const float r0 = 1.f / (dn0 + 1e-9f), r1 = 1.f / (dn1 + 1e-9f);
  const float r2 = 1.f / (dn2 + 1e-9f), r3 = 1.f / (dn3 + 1e-9f);

  const float xnx = xc[3 * n], xny = xc[3 * n + 1], xnz = xc[3 * n + 2];
  const int ch4 = tid & 31, jg = tid >> 5, hd = ch4 >> 3;
  float4 acc4 = make_float4(0.f, 0.f, 0.f, 0.f);
  float dxx = 0.f, dxy = 0.f, dxz = 0.f;

  for (int bs = 0; bs < deg; bs += 256) {
    int cnt = min(256, deg - bs);
    __syncthreads();
    if (tid < cnt) {
      int idx = st + bs + tid;
      float4 lg = cached ? sLg[bs + tid] : lg4[idx];
      float a0 = __expf(lg.x - m0) * r0;
      float a1 = __expf(lg.y - m1) * r1;
      float a2 = __expf(lg.z - m2) * r2;
      float a3 = __expf(lg.w - m3) * r3;
      int se = eS[idx];
      sA[tid][0] = a0; sA[tid][1] = a1; sA[tid][2] = a2; sA[tid][3] = a3;
      sSe[tid] = se;
      float rx = xc[3 * se + 0] - xnx;
      float ry = xc[3 * se + 1] - xny;
      float rz = xc[3 * se + 2] - xnz;
      float dd = rx * rx + ry * ry + rz * rz;
      float s = spre[idx] * (a0 + a1 + a2 + a3) * 0.25f;
      float inv = s / (sqrtf(dd) + 1.f);
      dxx += rx * inv; dxy += ry * inv; dxz += rz * inv;
    }
    __syncthreads();
    for (int j = jg; j < cnt; j += 8) {
      float a = sA[j][hd];
      const float4 v = *(const float4*)(hvin + (size_t)sSe[j] * CDIM + ch4 * 4);
      acc4.x += a * v.x; acc4.y += a * v.y;
      acc4.z += a * v.z; acc4.w += a * v.w;
    }
  }
  sAccF[jg][ch4] = acc4;
#pragma unroll
  for (int o = 32; o; o >>= 1) {
    dxx += __shfl_xor(dxx, o);
    dxy += __shfl_xor(dxy, o);
    dxz += __shfl_xor(dxz, o);
  }
  if (!lane) { sDx[w][0] = dxx; sDx[w][1] = dxy; sDx[w][2] = dxz; }
  __syncthreads();
  if (tid == 0) {
    xn[3 * n + 0] = xnx + sDx[0][0] + sDx[1][0] + sDx[2][0] + sDx[3][0];
    xn[3 * n + 1] = xny + sDx[0][1] + sDx[1][1] + sDx[2][1] + sDx[3][1];
    xn[3 * n + 2] = xnz + sDx[0][2] + sDx[1][2] + sDx[2][2] + sDx[3][2];
  }
  if (tid < 32) {
    float4 s = sAccF[0][tid];
#pragma unroll
    for (int g = 1; g < 8; ++g) {
      float4 v = sAccF[g][tid];
      s.x += v.x; s.y += v.y; s.z += v.z; s.w += v.w;
    }
    *(float4*)&agg[(size_t)n * CDIM + tid * 4] = s;
  }
  __syncthreads();
}

static __device__ void node_body(char* sm, int vb, const float* agg,
                                 const float* hin, const float* Wol,
                                 const float* gl, const float* bl,
                                 const float* Wqn, const float* Wkn,
                                 const float* Wvn, float* hout, float* hq,
                                 float* hk, float* hv) {
  float(*sAg)[128] = (float(*)[128])(sm);
  float(*sHin)[128] = (float(*)[128])(sm + 2048);
  float(*sW)[128] = (float(*)[128])(sm + 4096);
  float(*sH)[128] = (float(*)[128])(sm + 36864);
  float(*sRed)[2][2] = (float(*)[2][2])(sm + 38912);

  const int tid = threadIdx.x;
  const int c = tid & 127, g = tid >> 7;
  const int w = tid >> 6, lane = tid & 63;
  const int nb = vb * 4;

  {
    int i = tid & 127, half = tid >> 7;
    int n = i >> 5, t4 = i & 31;
    const float* srcb = half ? hin : agg;
    float* dstb = half ? &sHin[0][0] : &sAg[0][0];
    *(float4*)&dstb[n * 128 + t4 * 4] =
        *(const float4*)&srcb[(size_t)(nb + n) * CDIM + t4 * 4];
  }
  __syncthreads();

  float o0 = 0.f, o1 = 0.f;
  for (int kc = 0; kc < 2; ++kc) {
    const float4* wsrc = (const float4*)(Wol + (size_t)kc * 64 * CDIM);
#pragma unroll
    for (int i = 0; i < 8; ++i) ((float4*)sW)[tid + i * 256] = wsrc[tid + i * 256];
    __syncthreads();
#pragma unroll 8
    for (int k = 0; k < 64; ++k) {
      float wv = sW[k][c];
      o0 += sAg[g * 2][kc * 64 + k] * wv;
      o1 += sAg[g * 2 + 1][kc * 64 + k] * wv;
    }
    __syncthreads();
  }
  float hn0 = sHin[g * 2][c] + fmaxf(o0, 0.f);
  float hn1 = sHin[g * 2 + 1][c] + fmaxf(o1, 0.f);
  float s10 = hn0, s20 = hn0 * hn0, s11 = hn1, s21 = hn1 * hn1;
#pragma unroll
  for (int o = 32; o; o >>= 1) {
    s10 += __shfl_xor(s10, o); s20 += __shfl_xor(s20, o);
    s11 += __shfl_xor(s11, o); s21 += __shfl_xor(s21, o);
  }
  if (!lane) {
    sRed[w][0][0] = s10; sRed[w][0][1] = s20;
    sRed[w][1][0] = s11; sRed[w][1][1] = s21;
  }
  __syncthreads();
  {
    float t10 = sRed[g * 2][0][0] + sRed[g * 2 + 1][0][0];
    float t20 = sRed[g * 2][0][1] + sRed[g * 2 + 1][0][1];
    float t11 = sRed[g * 2][1][0] + sRed[g * 2 + 1][1][0];
    float t21 = sRed[g * 2][1][1] + sRed[g * 2 + 1][1][1];
    float mu0 = t10 * (1.f / 128.f), mu1 = t11 * (1.f / 128.f);
    float v0 = t20 * (1.f / 128.f) - mu0 * mu0;
    float v1 = t21 * (1.f / 128.f) - mu1 * mu1;
    float gg = gl[c], bb = bl[c];
    hn0 = (hn0 - mu0) * rsqrtf(v0 + 1e-5f) * gg + bb;
    hn1 = (hn1 - mu1) * rsqrtf(v1 + 1e-5f) * gg + bb;
  }
  hout[(size_t)(nb + g * 2) * CDIM + c] = hn0;
  hout[(size_t)(nb + g * 2 + 1) * CDIM + c] = hn1;
  sH[g * 2][c] = hn0;
  sH[g * 2 + 1][c] = hn1;
  __syncthreads();

  for (int ws = 0; ws < 3; ++ws) {
    const float* W = ws == 0 ? Wqn : (ws == 1 ? Wkn : Wvn);
    float b0 = 0.f, b1 = 0.f;
    for (int kc = 0; kc < 2; ++kc) {
      const float4* wsrc = (const float4*)(W + (size_t)kc * 64 * CDIM);
#pragma unroll
      for (int i = 0; i < 8; ++i) ((float4*)sW)[tid + i * 256] = wsrc[tid + i * 256];
      __syncthreads();
#pragma unroll 8
      for (int k = 0; k < 64; ++k) {
        float wv = sW[k][c];
        b0 += sH[g * 2][kc * 64 + k] * wv;
        b1 += sH[g * 2 + 1][kc * 64 + k] * wv;
      }
      __syncthreads();
    }
    float* o = ws == 0 ? hq : (ws == 1 ? hk : hv);
    o[(size_t)(nb + g * 2) * CDIM + c] = b0;
    o[(size_t)(nb + g * 2 + 1) * CDIM + c] = b1;
  }
  __syncthreads();
}

// ---------------- cooperative mega kernel ----------------
__global__ __launch_bounds__(256) void k_mega(MegaArgs A) {
  __shared__ __align__(16) char sm[SM_BYTES];
  cg::grid_group grid = cg::this_grid();
  const int gsz = gridDim.x;
  const int tid = threadIdx.x;

  for (int idx = blockIdx.x * 256 + tid; idx < NLAY * CDIM * CDIM;
       idx += gsz * 256) {
    int l = idx >> 14;
    int rem = idx & 16383;
    int cc = rem >> 7, k = rem & 127;
    A.WeT[idx] = f2bf(A.We[(size_t)(l * 129 + k) * 128 + cc]);
  }
  for (int vb = blockIdx.x; vb < NNODE / 4; vb += gsz)
    hinq_body(sm, vb, A.seq, A.Win, A.Wq, A.Wk, A.Wv, A.hA, A.hqA, A.hkA, A.hvA);
  grid.sync();

  const float* xc = A.coords;
  for (int l = 0; l < NLAY; ++l) {
    const float* hqi = (l & 1) ? A.hqB : A.hqA;
    const float* hki = (l & 1) ? A.hkB : A.hkA;
    const float* hvi = (l & 1) ? A.hvB : A.hvA;
    float* hqo = (l & 1) ? A.hqA : A.hqB;
    float* hko = (l & 1) ? A.hkA : A.hkB;
    float* hvo = (l & 1) ? A.hvA : A.hvB;
    const float* hin = (l & 1) ? A.hB : A.hA;
    float* hout = (l & 1) ? A.hA : A.hB;
    float* xn = (l == NLAY - 1) ? A.out : (l == 0 ? A.x0 : A.x1);

    for (int vb = blockIdx.x; vb < EMAX / 64; vb += gsz)
      edge_body(sm, vb, l == 0 ? 1 : 0, A.pair, A.bppm, A.eS, A.eD, A.Ebf,
                A.logits, A.spre, xc, hqi, hki,
                A.WeT + (size_t)l * CDIM * CDIM, A.We + (size_t)l * 129 * CDIM,
                A.wd + (size_t)l * CDIM, A.wx + (size_t)l * CDIM);
    grid.sync();

    for (int vb = blockIdx.x; vb < NNODE; vb += gsz)
      aggf_body(sm, vb, A.rowp, (const float4*)A.logits, A.spre, hvi, A.eS, xc,
                xn, A.agg);
    grid.sync();

    if (l < NLAY - 1) {
      for (int vb = blockIdx.x; vb < NNODE / 4; vb += gsz)
        node_body(sm, vb, A.agg, hin, A.Wo + (size_t)l * CDIM * CDIM,
                  A.lng + (size_t)l * CDIM, A.lnb + (size_t)l * CDIM,
                  A.Wq + (size_t)(l + 1) * CDIM * CDIM,
                  A.Wk + (size_t)(l + 1) * CDIM * CDIM,
                  A.Wv + (size_t)(l + 1) * CDIM * CDIM, hout, hqo, hko, hvo);
      grid.sync();
    }
    xc = xn;
  }
}

// ---------------- split-kernel fallbacks (R11-proven) ----------------
__global__ __launch_bounds__(256) void k_hinq(
    const float* __restrict__ seq, const float* __restrict__ Win,
    const float* __restrict__ Wq0, const float* __restrict__ Wk0,
    const float* __restrict__ Wv0, float* __restrict__ h,
    float* __restrict__ hq, float* __restrict__ hk, float* __restrict__ hv,
    const float* __restrict__ We, unsigned short* __restrict__ WeT) {
  __shared__ __align__(16) char sm[36 * 1024];
  if (blockIdx.x < 192) {
    int idx = blockIdx.x * 256 + threadIdx.x;
    int l = idx >> 14;
    int rem = idx & 16383;
    int cc = rem >> 7, k = rem & 127;
    WeT[idx] = f2bf(We[(size_t)(l * 129 + k) * 128 + cc]);
  }
  hinq_body(sm, blockIdx.x, seq, Win, Wq0, Wk0, Wv0, h, hq, hk, hv);
}

__global__ __launch_bounds__(256) void k_edge(
    const float* __restrict__ pair, const float* __restrict__ bppm,
    const int* __restrict__ eS, const int* __restrict__ eD,
    unsigned short* __restrict__ Ebf, float* __restrict__ logits,
    float* __restrict__ spre, const float* __restrict__ xc,
    const float* __restrict__ hq, const float* __restrict__ hk,
    const unsigned short* __restrict__ WeTl, const float* __restrict__ Wel,
    const float* __restrict__ wdl, const float* __restrict__ wxl, int gather) {
  __shared__ __align__(16) char sm[SM_BYTES];
  edge_body(sm, blockIdx.x, gather, pair, bppm, eS, eD, Ebf, logits, spre, xc,
            hq, hk, WeTl, Wel, wdl, wxl);
}

__global__ __launch_bounds__(256) void k_aggf(
    const int* __restrict__ rowp, const float4* __restrict__ lg4,
    const float* __restrict__ spre, const float* __restrict__ hvin,
    const int* __restrict__ eS, const float* __restrict__ xc,
    float* __restrict__ xn, float* __restrict__ agg) {
  __shared__ __align__(16) char sm[22 * 1024];
  aggf_body(sm, blockIdx.x, rowp, lg4, spre, hvin, eS, xc, xn, agg);
}

__global__ __launch_bounds__(256) void k_node(
    const float* __restrict__ agg, const float* __restrict__ hin,
    const float* __restrict__ Wol, const float* __restrict__ gl,
    const float* __restrict__ bl, const float* __restrict__ Wqn,
    const float* __restrict__ Wkn, const float* __restrict__ Wvn,
    float* __restrict__ hout, float* __restrict__ hq, float* __restrict__ hk,
    float* __restrict__ hv) {
  __shared__ __align__(16) char sm[39 * 1024];
  node_body(sm, blockIdx.x, agg, hin, Wol, gl, bl, Wqn, Wkn, Wvn, hout, hq, hk,
            hv);
}

// ---------------- launch ----------------
extern "C" void kernel_launch(void* const* d_in, const int* in_sizes, int n_in,
                              void* d_out, int out_size, void* d_ws, size_t ws_size,
                              hipStream_t stream) {
  const float* seq    = (const float*)d_in[0];
  const float* pair   = (const float*)d_in[1];
  const float* bppm   = (const float*)d_in[2];
  const float* coords = (const float*)d_in[3];
  const float* Win    = (const float*)d_in[4];
  const float* Wq     = (const float*)d_in[5];
  const float* Wk     = (const float*)d_in[6];
  const float* Wv     = (const float*)d_in[7];
  const float* Wo     = (const float*)d_in[8];
  const float* We     = (const float*)d_in[9];
  const float* wd     = (const float*)d_in[10];
  const float* wx     = (const float*)d_in[11];
  const float* lng    = (const float*)d_in[12];
  const float* lnb    = (const float*)d_in[13];
  const int*   src    = (const int*)d_in[14];
  const int*   dst    = (const int*)d_in[15];
  const float* emask  = (const float*)d_in[16];
  float* out = (float*)d_out;

  size_t off = 0;
  auto take = [&](size_t bytes) {
    void* p = (char*)d_ws + off;
    off += (bytes + 255) & ~(size_t)255;
    return p;
  };
  float* hA     = (float*)take((size_t)NNODE * CDIM * 4);
  float* hB     = (float*)take((size_t)NNODE * CDIM * 4);
  float* hqA    = (float*)take((size_t)NNODE * CDIM * 4);
  float* hkA    = (float*)take((size_t)NNODE * CDIM * 4);
  float* hvA    = (float*)take((size_t)NNODE * CDIM * 4);
  float* hqB    = (float*)take((size_t)NNODE * CDIM * 4);
  float* hkB    = (float*)take((size_t)NNODE * CDIM * 4);
  float* hvB    = (float*)take((size_t)NNODE * CDIM * 4);
  float* logits = (float*)take((size_t)EMAX * 4 * 4);
  float* spre   = (float*)take((size_t)EMAX * 4);
  float* agg    = (float*)take((size_t)NNODE * CDIM * 4);
  float* x0     = (float*)take((size_t)NNODE * 3 * 4);
  float* x1     = (float*)take((size_t)NNODE * 3 * 4);
  int*   meta   = (int*)take((size_t)(NNODE * 2 + 2 * EMAX) * 4);
  int*   cnt    = meta;
  int*   cur    = meta + NNODE;
  int*   eS     = meta + 2 * NNODE;
  int*   eD     = eS + EMAX;
  int*   rowp   = (int*)take((size_t)(NNODE + 1) * 4);
  unsigned short* Ebf = (unsigned short*)take((size_t)EMAX * CDIM * 2);
  unsigned short* WeT = (unsigned short*)take((size_t)NLAY * CDIM * CDIM * 2);

  k_zero<<<(NNODE * 2 + 2 * EMAX + 255) / 256, 256, 0, stream>>>(
      meta, NNODE * 2 + 2 * EMAX);
  k_count<<<EMAX / 256, 256, 0, stream>>>(dst, emask, cnt);
  k_scan<<<1, 256, 0, stream>>>(cnt, rowp);
  k_fill<<<EMAX / 256, 256, 0, stream>>>(src, dst, emask, rowp, cur, eS, eD);

  MegaArgs args;
  args.seq = seq; args.pair = pair; args.bppm = bppm; args.coords = coords;
  args.Win = Win; args.Wq = Wq; args.Wk = Wk; args.Wv = Wv; args.Wo = Wo;
  args.We = We; args.wd = wd; args.wx = wx; args.lng = lng; args.lnb = lnb;
  args.eS = eS; args.eD = eD; args.rowp = rowp;
  args.hA = hA; args.hB = hB;
  args.hqA = hqA; args.hkA = hkA; args.hvA = hvA;
  args.hqB = hqB; args.hkB = hkB; args.hvB = hvB;
  args.logits = logits; args.spre = spre; args.agg = agg;
  args.x0 = x0; args.x1 = x1; args.out = out;
  args.Ebf = Ebf; args.WeT = WeT;

  int cus = 0;
  hipDeviceGetAttribute(&cus, hipDeviceAttributeMultiprocessorCount, 0);
  if (cus <= 0) cus = 256;
  int perCU = 0;
  hipOccupancyMaxActiveBlocksPerMultiprocessor(&perCU, k_mega, 256, 0);
  if (perCU > 2) perCU = 2;

  hipError_t err = hipErrorUnknown;
  void* kargs[] = {&args};
  if (perCU >= 1) {
    err = hipLaunchCooperativeKernel((const void*)k_mega, dim3(perCU * cus),
                                     dim3(256), kargs, 0, stream);
    if (err != hipSuccess) (void)hipGetLastError();
  }
  if (err != hipSuccess) {  // retry at guaranteed-resident 1 block/CU
    err = hipLaunchCooperativeKernel((const void*)k_mega, dim3(cus), dim3(256),
                                     kargs, 0, stream);
    if (err != hipSuccess) (void)hipGetLastError();
  }
  if (err != hipSuccess) {
    // fallback: split-kernel sequence (R11-proven)
    k_hinq<<<NNODE / 4, 256, 0, stream>>>(seq, Win, Wq, Wk, Wv, hA, hqA, hkA,
                                          hvA, We, WeT);
    const float* xc = coords;
    for (int l = 0; l < NLAY; ++l) {
      const float* hqi = (l & 1) ? hqB : hqA;
      const float* hki = (l & 1) ? hkB : hkA;
      const float* hvi = (l & 1) ? hvB : hvA;
      float* hqo = (l & 1) ? hqA : hqB;
      float* hko = (l & 1) ? hkA : hkB;
      float* hvo = (l & 1) ? hvA : hvB;
      const float* hin = (l & 1) ? hB : hA;
      float* hout = (l & 1) ? hA : hB;

      k_edge<<<EMAX / 64, 256, 0, stream>>>(
          pair, bppm, eS, eD, Ebf, logits, spre, xc, hqi, hki,
          WeT + (size_t)l * CDIM * CDIM, We + (size_t)l * 129 * CDIM,
          wd + (size_t)l * CDIM, wx + (size_t)l * CDIM, l == 0 ? 1 : 0);

      float* xn = (l == NLAY - 1) ? out : (l == 0 ? x0 : x1);
      k_aggf<<<NNODE, 256, 0, stream>>>(rowp, (const float4*)logits, spre, hvi,
                                        eS, xc, xn, agg);
      if (l < NLAY - 1)
        k_node<<<NNODE / 4, 256, 0, stream>>>(
            agg, hin, Wo + (size_t)l * CDIM * CDIM, lng + (size_t)l * CDIM,
            lnb + (size_t)l * CDIM, Wq + (size_t)(l + 1) * CDIM * CDIM,
            Wk + (size_t)(l + 1) * CDIM * CDIM,
            Wv + (size_t)(l + 1) * CDIM * CDIM, hout, hqo, hko, hvo);
      xc = xn;
    }
  }
}

// Round 14
// 230.210 us; speedup vs baseline: 2.9820x; 2.9820x over previous
//
#include <hip/hip_runtime.h>

#define LSEQ  512
#define NNODE 2048
#define CDIM  128
#define EMAX  131072
#define NLAY  3
#define DCAP  768

typedef float f32x4 __attribute__((ext_vector_type(4)));
typedef unsigned short u16x8 __attribute__((ext_vector_type(8)));

static __device__ __forceinline__ unsigned short f2bf(float x) {
  unsigned u = __float_as_uint(x);
  unsigned r = (u + 0x7fffu + ((u >> 16) & 1u)) >> 16;
  return (unsigned short)r;
}

static __device__ __forceinline__ void mfma16(f32x4& d, f32x4 a, f32x4 b) {
  asm("v_mfma_f32_16x16x32_bf16 %0, %1, %2, %0" : "+v"(d) : "v"(a), "v"(b));
}

// ---------------- CSR build ----------------
__global__ void k_count(const int* __restrict__ dst, const float* __restrict__ msk,
                        int* __restrict__ cnt) {
  int e = blockIdx.x * 256 + threadIdx.x;
  if (msk[e] != 0.f) atomicAdd(&cnt[dst[e]], 1);
}

__global__ __launch_bounds__(256) void k_scan(const int* __restrict__ cnt,
                                              int* __restrict__ rowp) {
  __shared__ int lds[256];
  int t = threadIdx.x;
  int loc[8];
  int s = 0;
#pragma unroll
  for (int i = 0; i < 8; ++i) { loc[i] = s; s += cnt[t * 8 + i]; }
  lds[t] = s;
  __syncthreads();
  for (int off = 1; off < 256; off <<= 1) {
    int v = (t >= off) ? lds[t - off] : 0;
    __syncthreads();
    lds[t] += v;
    __syncthreads();
  }
  int base = t ? lds[t - 1] : 0;
#pragma unroll
  for (int i = 0; i < 8; ++i) rowp[t * 8 + i] = base + loc[i];
  if (t == 255) rowp[NNODE] = lds[255];
}

__global__ void k_fill(const int* __restrict__ src, const int* __restrict__ dst,
                       const float* __restrict__ msk, const int* __restrict__ rowp,
                       int* __restrict__ cur, int* __restrict__ eS,
                       int* __restrict__ eD) {
  int e = blockIdx.x * 256 + threadIdx.x;
  if (msk[e] != 0.f) {
    int n = dst[e];
    int slot = atomicAdd(&cur[n], 1);
    int p = rowp[n] + slot;
    eS[p] = src[e];
    eD[p] = n;
  }
}

// ------- h0 = seq @ W_in + layer-0 qkv (+ meta zero + WeT prep) -------
// 32-row weight chunks: LDS ~19.5 KB -> 8 blocks/CU
__global__ __launch_bounds__(256) void k_hinq(
    const float* __restrict__ seq, const float* __restrict__ Win,
    const float* __restrict__ Wq0, const float* __restrict__ Wk0,
    const float* __restrict__ Wv0, float* __restrict__ h,
    float* __restrict__ hq, float* __restrict__ hk, float* __restrict__ hv,
    const float* __restrict__ We, unsigned short* __restrict__ WeT,
    int* __restrict__ meta, int nmeta) {
  __shared__ float sSeq[4][32];
  __shared__ __align__(16) float sW[32][128];
  __shared__ float sH[4][128];
  const int tid = threadIdx.x;
  const int c = tid & 127, g = tid >> 7;
  const int nb = blockIdx.x * 4;

  for (int i = blockIdx.x * 256 + tid; i < nmeta; i += gridDim.x * 256)
    meta[i] = 0;
  if (blockIdx.x < 192) {  // WeT: We[:128,:] -> bf16 transposed [l][c][k]
    int idx = blockIdx.x * 256 + tid;
    int l = idx >> 14;
    int rem = idx & 16383;
    int cc = rem >> 7, k = rem & 127;
    WeT[idx] = f2bf(We[(size_t)(l * 129 + k) * 128 + cc]);
  }

  float a0 = 0.f, a1 = 0.f;
  for (int kc = 0; kc < 20; ++kc) {
    if (tid < 32) {
      int n = tid >> 3, t4 = tid & 7;
      *(float4*)&sSeq[n][t4 * 4] =
          *(const float4*)&seq[(size_t)(nb + n) * 640 + kc * 32 + t4 * 4];
    }
    const float4* wsrc = (const float4*)(Win + (size_t)kc * 32 * CDIM);
#pragma unroll
    for (int i = 0; i < 4; ++i) ((float4*)sW)[tid + i * 256] = wsrc[tid + i * 256];
    __syncthreads();
#pragma unroll 8
    for (int k = 0; k < 32; ++k) {
      float w = sW[k][c];
      a0 += sSeq[g * 2][k] * w;
      a1 += sSeq[g * 2 + 1][k] * w;
    }
    __syncthreads();
  }
  h[(size_t)(nb + g * 2) * CDIM + c] = a0;
  h[(size_t)(nb + g * 2 + 1) * CDIM + c] = a1;
  sH[g * 2][c] = a0;
  sH[g * 2 + 1][c] = a1;
  __syncthreads();

  for (int ws = 0; ws < 3; ++ws) {
    const float* W = ws == 0 ? Wq0 : (ws == 1 ? Wk0 : Wv0);
    float b0 = 0.f, b1 = 0.f;
    for (int kc = 0; kc < 4; ++kc) {
      const float4* wsrc = (const float4*)(W + (size_t)kc * 32 * CDIM);
#pragma unroll
      for (int i = 0; i < 4; ++i)
        ((float4*)sW)[tid + i * 256] = wsrc[tid + i * 256];
      __syncthreads();
#pragma unroll 8
      for (int k = 0; k < 32; ++k) {
        float w = sW[k][c];
        b0 += sH[g * 2][kc * 32 + k] * w;
        b1 += sH[g * 2 + 1][kc * 32 + k] * w;
      }
      __syncthreads();
    }
    float* o = ws == 0 ? hq : (ws == 1 ? hk : hv);
    o[(size_t)(nb + g * 2) * CDIM + c] = b0;
    o[(size_t)(nb + g * 2 + 1) * CDIM + c] = b1;
  }
}

// ---------------- fused MFMA edge kernel (LDS overlay: sA dead after MFMA,
// sEb overlays it -> 34.8 KB total -> 4 blocks/CU) ----------------
__global__ __launch_bounds__(256) void k_edge(
    const float* __restrict__ pair, const float* __restrict__ bppm,
    const int* __restrict__ eS, const int* __restrict__ eD,
    unsigned short* __restrict__ Ebf, float* __restrict__ logits,
    float* __restrict__ spre, const float* __restrict__ xc,
    const float* __restrict__ hq, const float* __restrict__ hk,
    const unsigned short* __restrict__ WeTl, const float* __restrict__ Wel,
    const float* __restrict__ wdl, const float* __restrict__ wxl, int gather) {
  __shared__ __align__(16) char sm[34816];
  unsigned char* sA = (unsigned char*)sm;            // [0, 16384) dead after MFMA
  float* sEb = (float*)sm;                           // [0, 32768) overlays sA
  float(*sPart)[64] = (float(*)[64])(sm + 32768);    // 1024
  int* sS = (int*)(sm + 33792);
  int* sD = (int*)(sm + 34048);
  float* sBp = (float*)(sm + 34304);
  float* sD2 = (float*)(sm + 34560);

  const int tid = threadIdx.x;
  const int w = tid >> 6, l = tid & 63;
  const int li = l & 15, gi = l >> 4;
  const int p0 = blockIdx.x * 64;

  f32x4 stg[4];
  if (!gather) {
    const f32x4* gE = (const f32x4*)((const char*)Ebf + (size_t)p0 * 256);
#pragma unroll
    for (int r = 0; r < 4; ++r) stg[r] = gE[r * 256 + tid];
  } else {
#pragma unroll
    for (int i = 0; i < 4; ++i) {
      int slot = tid + i * 256;
      int q = slot >> 4, t = slot & 15;
      int p = p0 + q;
      int s_ = eS[p], d_ = eD[p];
      int j = d_ - ((s_ >> 9) << 9);
      const float* rp = pair + ((size_t)s_ * LSEQ + j) * CDIM + t * 8;
      float4 v0 = *(const float4*)rp;
      float4 v1 = *(const float4*)(rp + 4);
      u16x8 ov;
      ov[0] = f2bf(v0.x); ov[1] = f2bf(v0.y); ov[2] = f2bf(v0.z); ov[3] = f2bf(v0.w);
      ov[4] = f2bf(v1.x); ov[5] = f2bf(v1.y); ov[6] = f2bf(v1.z); ov[7] = f2bf(v1.w);
      int m = q >> 4, lie = q & 15, ks = t >> 2, gie = t & 3;
      int rel = ((ks * 4 + m) * 64 + gie * 16 + lie) * 16;
      *(u16x8*)(sA + rel) = ov;
      *(u16x8*)((char*)Ebf + (size_t)p0 * 256 + rel) = ov;
    }
  }

  f32x4 bf[2][4];
#pragma unroll
  for (int nt = 0; nt < 2; ++nt) {
    int c = w * 32 + nt * 16 + li;
#pragma unroll
    for (int ks = 0; ks < 4; ++ks) {
      int k0 = ks * 32 + gi * 8;
      bf[nt][ks] = *(const f32x4*)((const char*)WeTl + (size_t)(c * 128 + k0) * 2);
    }
  }

  if (tid < 64) {
    int p = p0 + tid;
    int s_ = eS[p], d_ = eD[p];
    sS[tid] = s_; sD[tid] = d_;
    int j = d_ - ((s_ >> 9) << 9);
    float rx = xc[3 * s_ + 0] - xc[3 * d_ + 0];
    float ry = xc[3 * s_ + 1] - xc[3 * d_ + 1];
    float rz = xc[3 * s_ + 2] - xc[3 * d_ + 2];
    sD2[tid] = rx * rx + ry * ry + rz * rz;
    sBp[tid] = bppm[(size_t)s_ * LSEQ + j];
  }

  f32x4* sA4 = (f32x4*)sA;
  if (!gather) {
#pragma unroll
    for (int r = 0; r < 4; ++r) sA4[r * 256 + tid] = stg[r];
  }
  __syncthreads();

  f32x4 acc[4][2];
#pragma unroll
  for (int m = 0; m < 4; ++m)
#pragma unroll
    for (int nt = 0; nt < 2; ++nt) acc[m][nt] = (f32x4){0.f, 0.f, 0.f, 0.f};

#pragma unroll
  for (int ks = 0; ks < 4; ++ks) {
    f32x4 af[4];
#pragma unroll
    for (int m = 0; m < 4; ++m) af[m] = sA4[(ks * 4 + m) * 64 + l];
#pragma unroll
    for (int m = 0; m < 4; ++m) {
      mfma16(acc[m][0], af[m], bf[0][ks]);
      mfma16(acc[m][1], af[m], bf[1][ks]);
    }
  }
  __syncthreads();  // sA reads complete before sEb overwrites the region

  const int c0 = w * 32 + li, c1 = c0 + 16;
  const float w128_0 = Wel[128 * 128 + c0], w128_1 = Wel[128 * 128 + c1];
  const float wd0 = wdl[c0], wd1 = wdl[c1];
#pragma unroll
  for (int m = 0; m < 4; ++m) {
#pragma unroll
    for (int r = 0; r < 4; ++r) {
      int el = m * 16 + gi * 4 + r;
      float bp = sBp[el], d2v = sD2[el];
      float eb0 = fmaxf(acc[m][0][r] + bp * w128_0 + d2v * wd0, 0.f);
      float eb1 = fmaxf(acc[m][1][r] + bp * w128_1 + d2v * wd1, 0.f);
      int swz = (el & 7) << 2;
      sEb[el * 128 + (c0 ^ swz)] = eb0;
      sEb[el * 128 + (c1 ^ swz)] = eb1;
    }
  }
  __syncthreads();

  {
    const int s_ = sS[l], d_ = sD[l];
    const int swz = (l & 7) << 2;
    const float* hkr = hk + (size_t)s_ * CDIM + w * 32;
    const float* hqr = hq + (size_t)d_ * CDIM + w * 32;
    const float* wxr = wxl + w * 32;
    float lp = 0.f, sp = 0.f;
#pragma unroll
    for (int k = 0; k < 8; ++k) {
      f32x4 ebq = *(const f32x4*)&sEb[l * 128 + ((w * 32 + k * 4) ^ swz)];
      float4 hkq = *(const float4*)(hkr + k * 4);
      float4 hqq = *(const float4*)(hqr + k * 4);
      float4 wxq = *(const float4*)(wxr + k * 4);
      float keb0 = ebq[0] + hkq.x, keb1 = ebq[1] + hkq.y;
      float keb2 = ebq[2] + hkq.z, keb3 = ebq[3] + hkq.w;
      lp += hqq.x * keb0 + hqq.y * keb1 + hqq.z * keb2 + hqq.w * keb3;
      sp += wxq.x * keb0 + wxq.y * keb1 + wxq.z * keb2 + wxq.w * keb3;
    }
    logits[(size_t)(p0 + l) * 4 + w] = lp * 0.17677669529663689f;
    sPart[w][l] = sp;
  }
  __syncthreads();
  if (tid < 64)
    spre[p0 + tid] =
        tanhf(sPart[0][tid] + sPart[1][tid] + sPart[2][tid] + sPart[3][tid]);
}

// ---- segment softmax + alpha*v aggregation + dx (LDS-cached logits) ----
__global__ __launch_bounds__(256) void k_aggf(
    const int* __restrict__ rowp, const float4* __restrict__ lg4,
    const float* __restrict__ spre, const float* __restrict__ hvin,
    const int* __restrict__ eS, const float* __restrict__ xc,
    float* __restrict__ xn, float* __restrict__ agg) {
  const int n = blockIdx.x, tid = threadIdx.x;
  const int w = tid >> 6, lane = tid & 63;
  const int st = rowp[n], deg = rowp[n + 1] - st;

  __shared__ __align__(16) float4 sLg[DCAP];
  __shared__ float sA[256][4];
  __shared__ int sSe[256];
  __shared__ float sRed[4][4];
  __shared__ __align__(16) float4 sAccF[8][32];
  __shared__ float sDx[4][3];

  const bool cached = (deg <= DCAP);

  float m0 = -3e38f, m1 = -3e38f, m2 = -3e38f, m3 = -3e38f;
  for (int i = tid; i < deg; i += 256) {
    float4 lg = lg4[st + i];
    if (cached) sLg[i] = lg;
    m0 = fmaxf(m0, lg.x); m1 = fmaxf(m1, lg.y);
    m2 = fmaxf(m2, lg.z); m3 = fmaxf(m3, lg.w);
  }
#pragma unroll
  for (int o = 32; o; o >>= 1) {
    m0 = fmaxf(m0, __shfl_xor(m0, o)); m1 = fmaxf(m1, __shfl_xor(m1, o));
    m2 = fmaxf(m2, __shfl_xor(m2, o)); m3 = fmaxf(m3, __shfl_xor(m3, o));
  }
  if (!lane) { sRed[w][0] = m0; sRed[w][1] = m1; sRed[w][2] = m2; sRed[w][3] = m3; }
  __syncthreads();
  m0 = fmaxf(fmaxf(sRed[0][0], sRed[1][0]), fmaxf(sRed[2][0], sRed[3][0]));
  m1 = fmaxf(fmaxf(sRed[0][1], sRed[1][1]), fmaxf(sRed[2][1], sRed[3][1]));
  m2 = fmaxf(fmaxf(sRed[0][2], sRed[1][2]), fmaxf(sRed[2][2], sRed[3][2]));
  m3 = fmaxf(fmaxf(sRed[0][3], sRed[1][3]), fmaxf(sRed[2][3], sRed[3][3]));
  __syncthreads();

  float dn0 = 0.f, dn1 = 0.f, dn2 = 0.f, dn3 = 0.f;
  for (int i = tid; i < deg; i += 256) {
    float4 lg = cached ? sLg[i] : lg4[st + i];
    dn0 += __expf(lg.x - m0); dn1 += __expf(lg.y - m1);
    dn2 += __expf(lg.z - m2); dn3 += __expf(lg.w - m3);
  }
#pragma unroll
  for (int o = 32; o; o >>= 1) {
    dn0 += __shfl_xor(dn0, o); dn1 += __shfl_xor(dn1, o);
    dn2 += __shfl_xor(dn2, o); dn3 += __shfl_xor(dn3, o);
  }
  if (!lane) { sRed[w][0] = dn0; sRed[w][1] = dn1; sRed[w][2] = dn2; sRed[w][3] = dn3; }
  __syncthreads();
  dn0 = sRed[0][0] + sRed[1][0] + sRed[2][0] + sRed[3][0];
  dn1 = sRed[0][1] + sRed[1][1] + sRed[2][1] + sRed[3][1];
  dn2 = sRed[0][2] + sRed[1][2] + sRed[2][2] + sRed[3][2];
  dn3 = sRed[0][3] + sRed[1][3] + sRed[2][3] + sRed[3][3];
  const float r0 = 1.f / (dn0 + 1e-9f), r1 = 1.f / (dn1 + 1e-9f);
  const float r2 = 1.f / (dn2 + 1e-9f), r3 = 1.f / (dn3 + 1e-9f);

  const float xnx = xc[3 * n], xny = xc[3 * n + 1], xnz = xc[3 * n + 2];
  const int ch4 = tid & 31, jg = tid >> 5, hd = ch4 >> 3;
  float4 acc4 = make_float4(0.f, 0.f, 0.f, 0.f);
  float dxx = 0.f, dxy = 0.f, dxz = 0.f;

  for (int bs = 0; bs < deg; bs += 256) {
    int cnt = min(256, deg - bs);
    __syncthreads();
    if (tid < cnt) {
      int idx = st + bs + tid;
      float4 lg = cached ? sLg[bs + tid] : lg4[idx];
      float a0 = __expf(lg.x - m0) * r0;
      float a1 = __expf(lg.y - m1) * r1;
      float a2 = __expf(lg.z - m2) * r2;
      float a3 = __expf(lg.w - m3) * r3;
      int se = eS[idx];
      sA[tid][0] = a0; sA[tid][1] = a1; sA[tid][2] = a2; sA[tid][3] = a3;
      sSe[tid] = se;
      float rx = xc[3 * se + 0] - xnx;
      float ry = xc[3 * se + 1] - xny;
      float rz = xc[3 * se + 2] - xnz;
      float dd = rx * rx + ry * ry + rz * rz;
      float s = spre[idx] * (a0 + a1 + a2 + a3) * 0.25f;
      float inv = s / (sqrtf(dd) + 1.f);
      dxx += rx * inv; dxy += ry * inv; dxz += rz * inv;
    }
    __syncthreads();
    for (int j = jg; j < cnt; j += 8) {
      float a = sA[j][hd];
      const float4 v = *(const float4*)(hvin + (size_t)sSe[j] * CDIM + ch4 * 4);
      acc4.x += a * v.x; acc4.y += a * v.y;
      acc4.z += a * v.z; acc4.w += a * v.w;
    }
  }
  sAccF[jg][ch4] = acc4;
#pragma unroll
  for (int o = 32; o; o >>= 1) {
    dxx += __shfl_xor(dxx, o);
    dxy += __shfl_xor(dxy, o);
    dxz += __shfl_xor(dxz, o);
  }
  if (!lane) { sDx[w][0] = dxx; sDx[w][1] = dxy; sDx[w][2] = dxz; }
  __syncthreads();
  if (tid == 0) {
    xn[3 * n + 0] = xnx + sDx[0][0] + sDx[1][0] + sDx[2][0] + sDx[3][0];
    xn[3 * n + 1] = xny + sDx[0][1] + sDx[1][1] + sDx[2][1] + sDx[3][1];
    xn[3 * n + 2] = xnz + sDx[0][2] + sDx[1][2] + sDx[2][2] + sDx[3][2];
  }
  if (tid < 32) {
    float4 s = sAccF[0][tid];
#pragma unroll
    for (int g = 1; g < 8; ++g) {
      float4 v = sAccF[g][tid];
      s.x += v.x; s.y += v.y; s.z += v.z; s.w += v.w;
    }
    *(float4*)&agg[(size_t)n * CDIM + tid * 4] = s;
  }
}

// ---- h-update + LN + next-layer qkv (32-row weight chunks, ~22 KB LDS) ----
__global__ __launch_bounds__(256) void k_node(
    const float* __restrict__ agg, const float* __restrict__ hin,
    const float* __restrict__ Wol, const float* __restrict__ gl,
    const float* __restrict__ bl, const float* __restrict__ Wqn,
    const float* __restrict__ Wkn, const float* __restrict__ Wvn,
    float* __restrict__ hout, float* __restrict__ hq,
    float* __restrict__ hk, float* __restrict__ hv) {
  __shared__ float sAg[4][128];
  __shared__ float sHin[4][128];
  __shared__ __align__(16) float sW[32][128];
  __shared__ float sH[4][128];
  __shared__ float sRed[4][2][2];
  const int tid = threadIdx.x;
  const int c = tid & 127, g = tid >> 7;
  const int w = tid >> 6, lane = tid & 63;
  const int nb = blockIdx.x * 4;

  {
    int i = tid & 127, half = tid >> 7;
    int n = i >> 5, t4 = i & 31;
    const float* srcb = half ? hin : agg;
    float* dstb = half ? &sHin[0][0] : &sAg[0][0];
    *(float4*)&dstb[n * 128 + t4 * 4] =
        *(const float4*)&srcb[(size_t)(nb + n) * CDIM + t4 * 4];
  }
  __syncthreads();

  float o0 = 0.f, o1 = 0.f;
  for (int kc = 0; kc < 4; ++kc) {
    const float4* wsrc = (const float4*)(Wol + (size_t)kc * 32 * CDIM);
#pragma unroll
    for (int i = 0; i < 4; ++i) ((float4*)sW)[tid + i * 256] = wsrc[tid + i * 256];
    __syncthreads();
#pragma unroll 8
    for (int k = 0; k < 32; ++k) {
      float wv = sW[k][c];
      o0 += sAg[g * 2][kc * 32 + k] * wv;
      o1 += sAg[g * 2 + 1][kc * 32 + k] * wv;
    }
    __syncthreads();
  }
  float hn0 = sHin[g * 2][c] + fmaxf(o0, 0.f);
  float hn1 = sHin[g * 2 + 1][c] + fmaxf(o1, 0.f);
  float s10 = hn0, s20 = hn0 * hn0, s11 = hn1, s21 = hn1 * hn1;
#pragma unroll
  for (int o = 32; o; o >>= 1) {
    s10 += __shfl_xor(s10, o); s20 += __shfl_xor(s20, o);
    s11 += __shfl_xor(s11, o); s21 += __shfl_xor(s21, o);
  }
  if (!lane) {
    sRed[w][0][0] = s10; sRed[w][0][1] = s20;
    sRed[w][1][0] = s11; sRed[w][1][1] = s21;
  }
  __syncthreads();
  {
    float t10 = sRed[g * 2][0][0] + sRed[g * 2 + 1][0][0];
    float t20 = sRed[g * 2][0][1] + sRed[g * 2 + 1][0][1];
    float t11 = sRed[g * 2][1][0] + sRed[g * 2 + 1][1][0];
    float t21 = sRed[g * 2][1][1] + sRed[g * 2 + 1][1][1];
    float mu0 = t10 * (1.f / 128.f), mu1 = t11 * (1.f / 128.f);
    float v0 = t20 * (1.f / 128.f) - mu0 * mu0;
    float v1 = t21 * (1.f / 128.f) - mu1 * mu1;
    float gg = gl[c], bb = bl[c];
    hn0 = (hn0 - mu0) * rsqrtf(v0 + 1e-5f) * gg + bb;
    hn1 = (hn1 - mu1) * rsqrtf(v1 + 1e-5f) * gg + bb;
  }
  hout[(size_t)(nb + g * 2) * CDIM + c] = hn0;
  hout[(size_t)(nb + g * 2 + 1) * CDIM + c] = hn1;
  sH[g * 2][c] = hn0;
  sH[g * 2 + 1][c] = hn1;
  __syncthreads();

  for (int ws = 0; ws < 3; ++ws) {
    const float* W = ws == 0 ? Wqn : (ws == 1 ? Wkn : Wvn);
    float b0 = 0.f, b1 = 0.f;
    for (int kc = 0; kc < 4; ++kc) {
      const float4* wsrc = (const float4*)(W + (size_t)kc * 32 * CDIM);
#pragma unroll
      for (int i = 0; i < 4; ++i)
        ((float4*)sW)[tid + i * 256] = wsrc[tid + i * 256];
      __syncthreads();
#pragma unroll 8
      for (int k = 0; k < 32; ++k) {
        float wv = sW[k][c];
        b0 += sH[g * 2][kc * 32 + k] * wv;
        b1 += sH[g * 2 + 1][kc * 32 + k] * wv;
      }
      __syncthreads();
    }
    float* o = ws == 0 ? hq : (ws == 1 ? hk : hv);
    o[(size_t)(nb + g * 2) * CDIM + c] = b0;
    o[(size_t)(nb + g * 2 + 1) * CDIM + c] = b1;
  }
}

// ---------------- launch ----------------
extern "C" void kernel_launch(void* const* d_in, const int* in_sizes, int n_in,
                              void* d_out, int out_size, void* d_ws, size_t ws_size,
                              hipStream_t stream) {
  const float* seq    = (const float*)d_in[0];
  const float* pair   = (const float*)d_in[1];
  const float* bppm   = (const float*)d_in[2];
  const float* coords = (const float*)d_in[3];
  const float* Win    = (const float*)d_in[4];
  const float* Wq     = (const float*)d_in[5];
  const float* Wk     = (const float*)d_in[6];
  const float* Wv     = (const float*)d_in[7];
  const float* Wo     = (const float*)d_in[8];
  const float* We     = (const float*)d_in[9];
  const float* wd     = (const float*)d_in[10];
  const float* wx     = (const float*)d_in[11];
  const float* lng    = (const float*)d_in[12];
  const float* lnb    = (const float*)d_in[13];
  const int*   src    = (const int*)d_in[14];
  const int*   dst    = (const int*)d_in[15];
  const float* emask  = (const float*)d_in[16];
  float* out = (float*)d_out;

  size_t off = 0;
  auto take = [&](size_t bytes) {
    void* p = (char*)d_ws + off;
    off += (bytes + 255) & ~(size_t)255;
    return p;
  };
  float* hA     = (float*)take((size_t)NNODE * CDIM * 4);
  float* hB     = (float*)take((size_t)NNODE * CDIM * 4);
  float* hqA    = (float*)take((size_t)NNODE * CDIM * 4);
  float* hkA    = (float*)take((size_t)NNODE * CDIM * 4);
  float* hvA    = (float*)take((size_t)NNODE * CDIM * 4);
  float* hqB    = (float*)take((size_t)NNODE * CDIM * 4);
  float* hkB    = (float*)take((size_t)NNODE * CDIM * 4);
  float* hvB    = (float*)take((size_t)NNODE * CDIM * 4);
  float* logits = (float*)take((size_t)EMAX * 4 * 4);
  float* spre   = (float*)take((size_t)EMAX * 4);
  float* agg    = (float*)take((size_t)NNODE * CDIM * 4);
  float* x0     = (float*)take((size_t)NNODE * 3 * 4);
  float* x1     = (float*)take((size_t)NNODE * 3 * 4);
  int*   meta   = (int*)take((size_t)(NNODE * 2 + 2 * EMAX) * 4);
  int*   cnt    = meta;
  int*   cur    = meta + NNODE;
  int*   eS     = meta + 2 * NNODE;
  int*   eD     = eS + EMAX;
  int*   rowp   = (int*)take((size_t)(NNODE + 1) * 4);
  unsigned short* Ebf = (unsigned short*)take((size_t)EMAX * CDIM * 2);
  unsigned short* WeT = (unsigned short*)take((size_t)NLAY * CDIM * CDIM * 2);

  const int nmeta = NNODE * 2 + 2 * EMAX;

  // hinq also zeroes meta (cnt|cur|eS|eD) and preps WeT; runs first.
  k_hinq<<<NNODE / 4, 256, 0, stream>>>(seq, Win, Wq, Wk, Wv, hA, hqA, hkA, hvA,
                                        We, WeT, meta, nmeta);
  k_count<<<EMAX / 256, 256, 0, stream>>>(dst, emask, cnt);
  k_scan<<<1, 256, 0, stream>>>(cnt, rowp);
  k_fill<<<EMAX / 256, 256, 0, stream>>>(src, dst, emask, rowp, cur, eS, eD);

  const float* xc = coords;
  for (int l = 0; l < NLAY; ++l) {
    const float* hqi = (l & 1) ? hqB : hqA;
    const float* hki = (l & 1) ? hkB : hkA;
    const float* hvi = (l & 1) ? hvB : hvA;
    float* hqo = (l & 1) ? hqA : hqB;
    float* hko = (l & 1) ? hkA : hkB;
    float* hvo = (l & 1) ? hvA : hvB;
    const float* hin = (l & 1) ? hB : hA;
    float* hout = (l & 1) ? hA : hB;

    k_edge<<<EMAX / 64, 256, 0, stream>>>(
        pair, bppm, eS, eD, Ebf, logits, spre, xc, hqi, hki,
        WeT + (size_t)l * CDIM * CDIM, We + (size_t)l * 129 * CDIM,
        wd + (size_t)l * CDIM, wx + (size_t)l * CDIM, l == 0 ? 1 : 0);

    float* xn = (l == NLAY - 1) ? out : (l == 0 ? x0 : x1);
    k_aggf<<<NNODE, 256, 0, stream>>>(rowp, (const float4*)logits, spre, hvi,
                                      eS, xc, xn, agg);
    if (l < NLAY - 1)
      k_node<<<NNODE / 4, 256, 0, stream>>>(
          agg, hin, Wo + (size_t)l * CDIM * CDIM, lng + (size_t)l * CDIM,
          lnb + (size_t)l * CDIM, Wq + (size_t)(l + 1) * CDIM * CDIM,
          Wk + (size_t)(l + 1) * CDIM * CDIM, Wv + (size_t)(l + 1) * CDIM * CDIM,
          hout, hqo, hko, hvo);
    xc = xn;
  }
}

// Round 15
// 215.850 us; speedup vs baseline: 3.1804x; 1.0665x over previous
//
#include <hip/hip_runtime.h>

#define LSEQ  512
#define NNODE 2048
#define CDIM  128
#define EMAX  131072
#define NLAY  3
#define DCAP  768

typedef float f32x4 __attribute__((ext_vector_type(4)));
typedef unsigned short u16x8 __attribute__((ext_vector_type(8)));

static __device__ __forceinline__ unsigned short f2bf(float x) {
  unsigned u = __float_as_uint(x);
  unsigned r = (u + 0x7fffu + ((u >> 16) & 1u)) >> 16;
  return (unsigned short)r;
}

static __device__ __forceinline__ void mfma16(f32x4& d, f32x4 a, f32x4 b) {
  asm("v_mfma_f32_16x16x32_bf16 %0, %1, %2, %0" : "+v"(d) : "v"(a), "v"(b));
}

// ---------------- CSR build ----------------
__global__ void k_count(const int* __restrict__ dst, const float* __restrict__ msk,
                        int* __restrict__ cnt) {
  int e = blockIdx.x * 256 + threadIdx.x;
  if (msk[e] != 0.f) atomicAdd(&cnt[dst[e]], 1);
}

__global__ __launch_bounds__(256) void k_scan(const int* __restrict__ cnt,
                                              int* __restrict__ rowp) {
  __shared__ int lds[256];
  int t = threadIdx.x;
  int loc[8];
  int s = 0;
#pragma unroll
  for (int i = 0; i < 8; ++i) { loc[i] = s; s += cnt[t * 8 + i]; }
  lds[t] = s;
  __syncthreads();
  for (int off = 1; off < 256; off <<= 1) {
    int v = (t >= off) ? lds[t - off] : 0;
    __syncthreads();
    lds[t] += v;
    __syncthreads();
  }
  int base = t ? lds[t - 1] : 0;
#pragma unroll
  for (int i = 0; i < 8; ++i) rowp[t * 8 + i] = base + loc[i];
  if (t == 255) rowp[NNODE] = lds[255];
}

__global__ void k_fill(const int* __restrict__ src, const int* __restrict__ dst,
                       const float* __restrict__ msk, const int* __restrict__ rowp,
                       int* __restrict__ cur, int* __restrict__ eS,
                       int* __restrict__ eD) {
  int e = blockIdx.x * 256 + threadIdx.x;
  if (msk[e] != 0.f) {
    int n = dst[e];
    int slot = atomicAdd(&cur[n], 1);
    int p = rowp[n] + slot;
    eS[p] = src[e];
    eD[p] = n;
  }
}

// ------- h0 = seq @ W_in + layer-0 qkv, 64-row chunks (R11-proven) -------
// also zeroes meta (cnt|cur|eS|eD) and preps WeT
__global__ __launch_bounds__(256) void k_hinq(
    const float* __restrict__ seq, const float* __restrict__ Win,
    const float* __restrict__ Wq0, const float* __restrict__ Wk0,
    const float* __restrict__ Wv0, float* __restrict__ h,
    float* __restrict__ hq, float* __restrict__ hk, float* __restrict__ hv,
    const float* __restrict__ We, unsigned short* __restrict__ WeT,
    int* __restrict__ meta, int nmeta) {
  __shared__ float sSeq[4][64];
  __shared__ __align__(16) float sW[64][128];
  __shared__ float sH[4][128];
  const int tid = threadIdx.x;
  const int c = tid & 127, g = tid >> 7;
  const int nb = blockIdx.x * 4;

  for (int i = blockIdx.x * 256 + tid; i < nmeta; i += gridDim.x * 256)
    meta[i] = 0;
  if (blockIdx.x < 192) {  // WeT: We[:128,:] -> bf16 transposed [l][c][k]
    int idx = blockIdx.x * 256 + tid;
    int l = idx >> 14;
    int rem = idx & 16383;
    int cc = rem >> 7, k = rem & 127;
    WeT[idx] = f2bf(We[(size_t)(l * 129 + k) * 128 + cc]);
  }

  float a0 = 0.f, a1 = 0.f;
  for (int kc = 0; kc < 10; ++kc) {
    if (tid < 64) {
      int n = tid >> 4, t4 = tid & 15;
      *(float4*)&sSeq[n][t4 * 4] =
          *(const float4*)&seq[(size_t)(nb + n) * 640 + kc * 64 + t4 * 4];
    }
    const float4* wsrc = (const float4*)(Win + (size_t)kc * 64 * CDIM);
#pragma unroll
    for (int i = 0; i < 8; ++i) ((float4*)sW)[tid + i * 256] = wsrc[tid + i * 256];
    __syncthreads();
#pragma unroll 8
    for (int k = 0; k < 64; ++k) {
      float w = sW[k][c];
      a0 += sSeq[g * 2][k] * w;
      a1 += sSeq[g * 2 + 1][k] * w;
    }
    __syncthreads();
  }
  h[(size_t)(nb + g * 2) * CDIM + c] = a0;
  h[(size_t)(nb + g * 2 + 1) * CDIM + c] = a1;
  sH[g * 2][c] = a0;
  sH[g * 2 + 1][c] = a1;
  __syncthreads();

  for (int ws = 0; ws < 3; ++ws) {
    const float* W = ws == 0 ? Wq0 : (ws == 1 ? Wk0 : Wv0);
    float b0 = 0.f, b1 = 0.f;
    for (int kc = 0; kc < 2; ++kc) {
      const float4* wsrc = (const float4*)(W + (size_t)kc * 64 * CDIM);
#pragma unroll
      for (int i = 0; i < 8; ++i) ((float4*)sW)[tid + i * 256] = wsrc[tid + i * 256];
      __syncthreads();
#pragma unroll 8
      for (int k = 0; k < 64; ++k) {
        float w = sW[k][c];
        b0 += sH[g * 2][kc * 64 + k] * w;
        b1 += sH[g * 2 + 1][kc * 64 + k] * w;
      }
      __syncthreads();
    }
    float* o = ws == 0 ? hq : (ws == 1 ? hk : hv);
    o[(size_t)(nb + g * 2) * CDIM + c] = b0;
    o[(size_t)(nb + g * 2 + 1) * CDIM + c] = b1;
  }
}

// ---------------- fused MFMA edge kernel (LDS overlay, 34.8 KB) ----------------
__global__ __launch_bounds__(256) void k_edge(
    const float* __restrict__ pair, const float* __restrict__ bppm,
    const int* __restrict__ eS, const int* __restrict__ eD,
    unsigned short* __restrict__ Ebf, float* __restrict__ logits,
    float* __restrict__ spre, const float* __restrict__ xc,
    const float* __restrict__ hq, const float* __restrict__ hk,
    const unsigned short* __restrict__ WeTl, const float* __restrict__ Wel,
    const float* __restrict__ wdl, const float* __restrict__ wxl, int gather) {
  __shared__ __align__(16) char sm[34816];
  unsigned char* sA = (unsigned char*)sm;            // dead after MFMA loop
  float* sEb = (float*)sm;                           // overlays sA
  float(*sPart)[64] = (float(*)[64])(sm + 32768);
  int* sS = (int*)(sm + 33792);
  int* sD = (int*)(sm + 34048);
  float* sBp = (float*)(sm + 34304);
  float* sD2 = (float*)(sm + 34560);

  const int tid = threadIdx.x;
  const int w = tid >> 6, l = tid & 63;
  const int li = l & 15, gi = l >> 4;
  const int p0 = blockIdx.x * 64;

  f32x4 stg[4];
  if (!gather) {
    const f32x4* gE = (const f32x4*)((const char*)Ebf + (size_t)p0 * 256);
#pragma unroll
    for (int r = 0; r < 4; ++r) stg[r] = gE[r * 256 + tid];
  } else {
#pragma unroll
    for (int i = 0; i < 4; ++i) {
      int slot = tid + i * 256;
      int q = slot >> 4, t = slot & 15;
      int p = p0 + q;
      int s_ = eS[p], d_ = eD[p];
      int j = d_ - ((s_ >> 9) << 9);
      const float* rp = pair + ((size_t)s_ * LSEQ + j) * CDIM + t * 8;
      float4 v0 = *(const float4*)rp;
      float4 v1 = *(const float4*)(rp + 4);
      u16x8 ov;
      ov[0] = f2bf(v0.x); ov[1] = f2bf(v0.y); ov[2] = f2bf(v0.z); ov[3] = f2bf(v0.w);
      ov[4] = f2bf(v1.x); ov[5] = f2bf(v1.y); ov[6] = f2bf(v1.z); ov[7] = f2bf(v1.w);
      int m = q >> 4, lie = q & 15, ks = t >> 2, gie = t & 3;
      int rel = ((ks * 4 + m) * 64 + gie * 16 + lie) * 16;
      *(u16x8*)(sA + rel) = ov;
      *(u16x8*)((char*)Ebf + (size_t)p0 * 256 + rel) = ov;
    }
  }

  f32x4 bf[2][4];
#pragma unroll
  for (int nt = 0; nt < 2; ++nt) {
    int c = w * 32 + nt * 16 + li;
#pragma unroll
    for (int ks = 0; ks < 4; ++ks) {
      int k0 = ks * 32 + gi * 8;
      bf[nt][ks] = *(const f32x4*)((const char*)WeTl + (size_t)(c * 128 + k0) * 2);
    }
  }

  if (tid < 64) {
    int p = p0 + tid;
    int s_ = eS[p], d_ = eD[p];
    sS[tid] = s_; sD[tid] = d_;
    int j = d_ - ((s_ >> 9) << 9);
    float rx = xc[3 * s_ + 0] - xc[3 * d_ + 0];
    float ry = xc[3 * s_ + 1] - xc[3 * d_ + 1];
    float rz = xc[3 * s_ + 2] - xc[3 * d_ + 2];
    sD2[tid] = rx * rx + ry * ry + rz * rz;
    sBp[tid] = bppm[(size_t)s_ * LSEQ + j];
  }

  f32x4* sA4 = (f32x4*)sA;
  if (!gather) {
#pragma unroll
    for (int r = 0; r < 4; ++r) sA4[r * 256 + tid] = stg[r];
  }
  __syncthreads();

  f32x4 acc[4][2];
#pragma unroll
  for (int m = 0; m < 4; ++m)
#pragma unroll
    for (int nt = 0; nt < 2; ++nt) acc[m][nt] = (f32x4){0.f, 0.f, 0.f, 0.f};

#pragma unroll
  for (int ks = 0; ks < 4; ++ks) {
    f32x4 af[4];
#pragma unroll
    for (int m = 0; m < 4; ++m) af[m] = sA4[(ks * 4 + m) * 64 + l];
#pragma unroll
    for (int m = 0; m < 4; ++m) {
      mfma16(acc[m][0], af[m], bf[0][ks]);
      mfma16(acc[m][1], af[m], bf[1][ks]);
    }
  }
  __syncthreads();  // sA reads complete before sEb overwrites

  const int c0 = w * 32 + li, c1 = c0 + 16;
  const float w128_0 = Wel[128 * 128 + c0], w128_1 = Wel[128 * 128 + c1];
  const float wd0 = wdl[c0], wd1 = wdl[c1];
#pragma unroll
  for (int m = 0; m < 4; ++m) {
#pragma unroll
    for (int r = 0; r < 4; ++r) {
      int el = m * 16 + gi * 4 + r;
      float bp = sBp[el], d2v = sD2[el];
      float eb0 = fmaxf(acc[m][0][r] + bp * w128_0 + d2v * wd0, 0.f);
      float eb1 = fmaxf(acc[m][1][r] + bp * w128_1 + d2v * wd1, 0.f);
      int swz = (el & 7) << 2;
      sEb[el * 128 + (c0 ^ swz)] = eb0;
      sEb[el * 128 + (c1 ^ swz)] = eb1;
    }
  }
  __syncthreads();

  {
    const int s_ = sS[l], d_ = sD[l];
    const int swz = (l & 7) << 2;
    const float* hkr = hk + (size_t)s_ * CDIM + w * 32;
    const float* hqr = hq + (size_t)d_ * CDIM + w * 32;
    const float* wxr = wxl + w * 32;
    float lp = 0.f, sp = 0.f;
#pragma unroll
    for (int k = 0; k < 8; ++k) {
      f32x4 ebq = *(const f32x4*)&sEb[l * 128 + ((w * 32 + k * 4) ^ swz)];
      float4 hkq = *(const float4*)(hkr + k * 4);
      float4 hqq = *(const float4*)(hqr + k * 4);
      float4 wxq = *(const float4*)(wxr + k * 4);
      float keb0 = ebq[0] + hkq.x, keb1 = ebq[1] + hkq.y;
      float keb2 = ebq[2] + hkq.z, keb3 = ebq[3] + hkq.w;
      lp += hqq.x * keb0 + hqq.y * keb1 + hqq.z * keb2 + hqq.w * keb3;
      sp += wxq.x * keb0 + wxq.y * keb1 + wxq.z * keb2 + wxq.w * keb3;
    }
    logits[(size_t)(p0 + l) * 4 + w] = lp * 0.17677669529663689f;
    sPart[w][l] = sp;
  }
  __syncthreads();
  if (tid < 64)
    spre[p0 + tid] =
        tanhf(sPart[0][tid] + sPart[1][tid] + sPart[2][tid] + sPart[3][tid]);
}

// ---- segment softmax + alpha*v aggregation + dx (LDS-cached logits) ----
__global__ __launch_bounds__(256) void k_aggf(
    const int* __restrict__ rowp, const float4* __restrict__ lg4,
    const float* __restrict__ spre, const float* __restrict__ hvin,
    const int* __restrict__ eS, const float* __restrict__ xc,
    float* __restrict__ xn, float* __restrict__ agg) {
  const int n = blockIdx.x, tid = threadIdx.x;
  const int w = tid >> 6, lane = tid & 63;
  const int st = rowp[n], deg = rowp[n + 1] - st;

  __shared__ __align__(16) float4 sLg[DCAP];
  __shared__ float sA[256][4];
  __shared__ int sSe[256];
  __shared__ float sRed[4][4];
  __shared__ __align__(16) float4 sAccF[8][32];
  __shared__ float sDx[4][3];

  const bool cached = (deg <= DCAP);

  float m0 = -3e38f, m1 = -3e38f, m2 = -3e38f, m3 = -3e38f;
  for (int i = tid; i < deg; i += 256) {
    float4 lg = lg4[st + i];
    if (cached) sLg[i] = lg;
    m0 = fmaxf(m0, lg.x); m1 = fmaxf(m1, lg.y);
    m2 = fmaxf(m2, lg.z); m3 = fmaxf(m3, lg.w);
  }
#pragma unroll
  for (int o = 32; o; o >>= 1) {
    m0 = fmaxf(m0, __shfl_xor(m0, o)); m1 = fmaxf(m1, __shfl_xor(m1, o));
    m2 = fmaxf(m2, __shfl_xor(m2, o)); m3 = fmaxf(m3, __shfl_xor(m3, o));
  }
  if (!lane) { sRed[w][0] = m0; sRed[w][1] = m1; sRed[w][2] = m2; sRed[w][3] = m3; }
  __syncthreads();
  m0 = fmaxf(fmaxf(sRed[0][0], sRed[1][0]), fmaxf(sRed[2][0], sRed[3][0]));
  m1 = fmaxf(fmaxf(sRed[0][1], sRed[1][1]), fmaxf(sRed[2][1], sRed[3][1]));
  m2 = fmaxf(fmaxf(sRed[0][2], sRed[1][2]), fmaxf(sRed[2][2], sRed[3][2]));
  m3 = fmaxf(fmaxf(sRed[0][3], sRed[1][3]), fmaxf(sRed[2][3], sRed[3][3]));
  __syncthreads();

  float dn0 = 0.f, dn1 = 0.f, dn2 = 0.f, dn3 = 0.f;
  for (int i = tid; i < deg; i += 256) {
    float4 lg = cached ? sLg[i] : lg4[st + i];
    dn0 += __expf(lg.x - m0); dn1 += __expf(lg.y - m1);
    dn2 += __expf(lg.z - m2); dn3 += __expf(lg.w - m3);
  }
#pragma unroll
  for (int o = 32; o; o >>= 1) {
    dn0 += __shfl_xor(dn0, o); dn1 += __shfl_xor(dn1, o);
    dn2 += __shfl_xor(dn2, o); dn3 += __shfl_xor(dn3, o);
  }
  if (!lane) { sRed[w][0] = dn0; sRed[w][1] = dn1; sRed[w][2] = dn2; sRed[w][3] = dn3; }
  __syncthreads();
  dn0 = sRed[0][0] + sRed[1][0] + sRed[2][0] + sRed[3][0];
  dn1 = sRed[0][1] + sRed[1][1] + sRed[2][1] + sRed[3][1];
  dn2 = sRed[0][2] + sRed[1][2] + sRed[2][2] + sRed[3][2];
  dn3 = sRed[0][3] + sRed[1][3] + sRed[2][3] + sRed[3][3];
  const float r0 = 1.f / (dn0 + 1e-9f), r1 = 1.f / (dn1 + 1e-9f);
  const float r2 = 1.f / (dn2 + 1e-9f), r3 = 1.f / (dn3 + 1e-9f);

  const float xnx = xc[3 * n], xny = xc[3 * n + 1], xnz = xc[3 * n + 2];
  const int ch4 = tid & 31, jg = tid >> 5, hd = ch4 >> 3;
  float4 acc4 = make_float4(0.f, 0.f, 0.f, 0.f);
  float dxx = 0.f, dxy = 0.f, dxz = 0.f;

  for (int bs = 0; bs < deg; bs += 256) {
    int cnt = min(256, deg - bs);
    __syncthreads();
    if (tid < cnt) {
      int idx = st + bs + tid;
      float4 lg = cached ? sLg[bs + tid] : lg4[idx];
      float a0 = __expf(lg.x - m0) * r0;
      float a1 = __expf(lg.y - m1) * r1;
      float a2 = __expf(lg.z - m2) * r2;
      float a3 = __expf(lg.w - m3) * r3;
      int se = eS[idx];
      sA[tid][0] = a0; sA[tid][1] = a1; sA[tid][2] = a2; sA[tid][3] = a3;
      sSe[tid] = se;
      float rx = xc[3 * se + 0] - xnx;
      float ry = xc[3 * se + 1] - xny;
      float rz = xc[3 * se + 2] - xnz;
      float dd = rx * rx + ry * ry + rz * rz;
      float s = spre[idx] * (a0 + a1 + a2 + a3) * 0.25f;
      float inv = s / (sqrtf(dd) + 1.f);
      dxx += rx * inv; dxy += ry * inv; dxz += rz * inv;
    }
    __syncthreads();
    for (int j = jg; j < cnt; j += 8) {
      float a = sA[j][hd];
      const float4 v = *(const float4*)(hvin + (size_t)sSe[j] * CDIM + ch4 * 4);
      acc4.x += a * v.x; acc4.y += a * v.y;
      acc4.z += a * v.z; acc4.w += a * v.w;
    }
  }
  sAccF[jg][ch4] = acc4;
#pragma unroll
  for (int o = 32; o; o >>= 1) {
    dxx += __shfl_xor(dxx, o);
    dxy += __shfl_xor(dxy, o);
    dxz += __shfl_xor(dxz, o);
  }
  if (!lane) { sDx[w][0] = dxx; sDx[w][1] = dxy; sDx[w][2] = dxz; }
  __syncthreads();
  if (tid == 0) {
    xn[3 * n + 0] = xnx + sDx[0][0] + sDx[1][0] + sDx[2][0] + sDx[3][0];
    xn[3 * n + 1] = xny + sDx[0][1] + sDx[1][1] + sDx[2][1] + sDx[3][1];
    xn[3 * n + 2] = xnz + sDx[0][2] + sDx[1][2] + sDx[2][2] + sDx[3][2];
  }
  if (tid < 32) {
    float4 s = sAccF[0][tid];
#pragma unroll
    for (int g = 1; g < 8; ++g) {
      float4 v = sAccF[g][tid];
      s.x += v.x; s.y += v.y; s.z += v.z; s.w += v.w;
    }
    *(float4*)&agg[(size_t)n * CDIM + tid * 4] = s;
  }
}

// ---- h-update + LN + next-layer qkv, 64-row chunks (R11-proven) ----
__global__ __launch_bounds__(256) void k_node(
    const float* __restrict__ agg, const float* __restrict__ hin,
    const float* __restrict__ Wol, const float* __restrict__ gl,
    const float* __restrict__ bl, const float* __restrict__ Wqn,
    const float* __restrict__ Wkn, const float* __restrict__ Wvn,
    float* __restrict__ hout, float* __restrict__ hq,
    float* __restrict__ hk, float* __restrict__ hv) {
  __shared__ float sAg[4][128];
  __shared__ float sHin[4][128];
  __shared__ __align__(16) float sW[64][128];
  __shared__ float sH[4][128];
  __shared__ float sRed[4][2][2];
  const int tid = threadIdx.x;
  const int c = tid & 127, g = tid >> 7;
  const int w = tid >> 6, lane = tid & 63;
  const int nb = blockIdx.x * 4;

  {
    int i = tid & 127, half = tid >> 7;
    int n = i >> 5, t4 = i & 31;
    const float* srcb = half ? hin : agg;
    float* dstb = half ? &sHin[0][0] : &sAg[0][0];
    *(float4*)&dstb[n * 128 + t4 * 4] =
        *(const float4*)&srcb[(size_t)(nb + n) * CDIM + t4 * 4];
  }
  __syncthreads();

  float o0 = 0.f, o1 = 0.f;
  for (int kc = 0; kc < 2; ++kc) {
    const float4* wsrc = (const float4*)(Wol + (size_t)kc * 64 * CDIM);
#pragma unroll
    for (int i = 0; i < 8; ++i) ((float4*)sW)[tid + i * 256] = wsrc[tid + i * 256];
    __syncthreads();
#pragma unroll 8
    for (int k = 0; k < 64; ++k) {
      float wv = sW[k][c];
      o0 += sAg[g * 2][kc * 64 + k] * wv;
      o1 += sAg[g * 2 + 1][kc * 64 + k] * wv;
    }
    __syncthreads();
  }
  float hn0 = sHin[g * 2][c] + fmaxf(o0, 0.f);
  float hn1 = sHin[g * 2 + 1][c] + fmaxf(o1, 0.f);
  float s10 = hn0, s20 = hn0 * hn0, s11 = hn1, s21 = hn1 * hn1;
#pragma unroll
  for (int o = 32; o; o >>= 1) {
    s10 += __shfl_xor(s10, o); s20 += __shfl_xor(s20, o);
    s11 += __shfl_xor(s11, o); s21 += __shfl_xor(s21, o);
  }
  if (!lane) {
    sRed[w][0][0] = s10; sRed[w][0][1] = s20;
    sRed[w][1][0] = s11; sRed[w][1][1] = s21;
  }
  __syncthreads();
  {
    float t10 = sRed[g * 2][0][0] + sRed[g * 2 + 1][0][0];
    float t20 = sRed[g * 2][0][1] + sRed[g * 2 + 1][0][1];
    float t11 = sRed[g * 2][1][0] + sRed[g * 2 + 1][1][0];
    float t21 = sRed[g * 2][1][1] + sRed[g * 2 + 1][1][1];
    float mu0 = t10 * (1.f / 128.f), mu1 = t11 * (1.f / 128.f);
    float v0 = t20 * (1.f / 128.f) - mu0 * mu0;
    float v1 = t21 * (1.f / 128.f) - mu1 * mu1;
    float gg = gl[c], bb = bl[c];
    hn0 = (hn0 - mu0) * rsqrtf(v0 + 1e-5f) * gg + bb;
    hn1 = (hn1 - mu1) * rsqrtf(v1 + 1e-5f) * gg + bb;
  }
  hout[(size_t)(nb + g * 2) * CDIM + c] = hn0;
  hout[(size_t)(nb + g * 2 + 1) * CDIM + c] = hn1;
  sH[g * 2][c] = hn0;
  sH[g * 2 + 1][c] = hn1;
  __syncthreads();

  for (int ws = 0; ws < 3; ++ws) {
    const float* W = ws == 0 ? Wqn : (ws == 1 ? Wkn : Wvn);
    float b0 = 0.f, b1 = 0.f;
    for (int kc = 0; kc < 2; ++kc) {
      const float4* wsrc = (const float4*)(W + (size_t)kc * 64 * CDIM);
#pragma unroll
      for (int i = 0; i < 8; ++i) ((float4*)sW)[tid + i * 256] = wsrc[tid + i * 256];
      __syncthreads();
#pragma unroll 8
      for (int k = 0; k < 64; ++k) {
        float wv = sW[k][c];
        b0 += sH[g * 2][kc * 64 + k] * wv;
        b1 += sH[g * 2 + 1][kc * 64 + k] * wv;
      }
      __syncthreads();
    }
    float* o = ws == 0 ? hq : (ws == 1 ? hk : hv);
    o[(size_t)(nb + g * 2) * CDIM + c] = b0;
    o[(size_t)(nb + g * 2 + 1) * CDIM + c] = b1;
  }
}

// ---------------- launch ----------------
extern "C" void kernel_launch(void* const* d_in, const int* in_sizes, int n_in,
                              void* d_out, int out_size, void* d_ws, size_t ws_size,
                              hipStream_t stream) {
  const float* seq    = (const float*)d_in[0];
  const float* pair   = (const float*)d_in[1];
  const float* bppm   = (const float*)d_in[2];
  const float* coords = (const float*)d_in[3];
  const float* Win    = (const float*)d_in[4];
  const float* Wq     = (const float*)d_in[5];
  const float* Wk     = (const float*)d_in[6];
  const float* Wv     = (const float*)d_in[7];
  const float* Wo     = (const float*)d_in[8];
  const float* We     = (const float*)d_in[9];
  const float* wd     = (const float*)d_in[10];
  const float* wx     = (const float*)d_in[11];
  const float* lng    = (const float*)d_in[12];
  const float* lnb    = (const float*)d_in[13];
  const int*   src    = (const int*)d_in[14];
  const int*   dst    = (const int*)d_in[15];
  const float* emask  = (const float*)d_in[16];
  float* out = (float*)d_out;

  size_t off = 0;
  auto take = [&](size_t bytes) {
    void* p = (char*)d_ws + off;
    off += (bytes + 255) & ~(size_t)255;
    return p;
  };
  float* hA     = (float*)take((size_t)NNODE * CDIM * 4);
  float* hB     = (float*)take((size_t)NNODE * CDIM * 4);
  float* hqA    = (float*)take((size_t)NNODE * CDIM * 4);
  float* hkA    = (float*)take((size_t)NNODE * CDIM * 4);
  float* hvA    = (float*)take((size_t)NNODE * CDIM * 4);
  float* hqB    = (float*)take((size_t)NNODE * CDIM * 4);
  float* hkB    = (float*)take((size_t)NNODE * CDIM * 4);
  float* hvB    = (float*)take((size_t)NNODE * CDIM * 4);
  float* logits = (float*)take((size_t)EMAX * 4 * 4);
  float* spre   = (float*)take((size_t)EMAX * 4);
  float* agg    = (float*)take((size_t)NNODE * CDIM * 4);
  float* x0     = (float*)take((size_t)NNODE * 3 * 4);
  float* x1     = (float*)take((size_t)NNODE * 3 * 4);
  int*   meta   = (int*)take((size_t)(NNODE * 2 + 2 * EMAX) * 4);
  int*   cnt    = meta;
  int*   cur    = meta + NNODE;
  int*   eS     = meta + 2 * NNODE;
  int*   eD     = eS + EMAX;
  int*   rowp   = (int*)take((size_t)(NNODE + 1) * 4);
  unsigned short* Ebf = (unsigned short*)take((size_t)EMAX * CDIM * 2);
  unsigned short* WeT = (unsigned short*)take((size_t)NLAY * CDIM * CDIM * 2);

  const int nmeta = NNODE * 2 + 2 * EMAX;

  k_hinq<<<NNODE / 4, 256, 0, stream>>>(seq, Win, Wq, Wk, Wv, hA, hqA, hkA, hvA,
                                        We, WeT, meta, nmeta);
  k_count<<<EMAX / 256, 256, 0, stream>>>(dst, emask, cnt);
  k_scan<<<1, 256, 0, stream>>>(cnt, rowp);
  k_fill<<<EMAX / 256, 256, 0, stream>>>(src, dst, emask, rowp, cur, eS, eD);

  const float* xc = coords;
  for (int l = 0; l < NLAY; ++l) {
    const float* hqi = (l & 1) ? hqB : hqA;
    const float* hki = (l & 1) ? hkB : hkA;
    const float* hvi = (l & 1) ? hvB : hvA;
    float* hqo = (l & 1) ? hqA : hqB;
    float* hko = (l & 1) ? hkA : hkB;
    float* hvo = (l & 1) ? hvA : hvB;
    const float* hin = (l & 1) ? hB : hA;
    float* hout = (l & 1) ? hA : hB;

    k_edge<<<EMAX / 64, 256, 0, stream>>>(
        pair, bppm, eS, eD, Ebf, logits, spre, xc, hqi, hki,
        WeT + (size_t)l * CDIM * CDIM, We + (size_t)l * 129 * CDIM,
        wd + (size_t)l * CDIM, wx + (size_t)l * CDIM, l == 0 ? 1 : 0);

    float* xn = (l == NLAY - 1) ? out : (l == 0 ? x0 : x1);
    k_aggf<<<NNODE, 256, 0, stream>>>(rowp, (const float4*)logits, spre, hvi,
                                      eS, xc, xn, agg);
    if (l < NLAY - 1)
      k_node<<<NNODE / 4, 256, 0, stream>>>(
          agg, hin, Wo + (size_t)l * CDIM * CDIM, lng + (size_t)l * CDIM,
          lnb + (size_t)l * CDIM, Wq + (size_t)(l + 1) * CDIM * CDIM,
          Wk + (size_t)(l + 1) * CDIM * CDIM, Wv + (size_t)(l + 1) * CDIM * CDIM,
          hout, hqo, hko, hvo);
    xc = xn;
  }
}